// Round 10
// baseline (520.868 us; speedup 1.0000x reference)
//
#include <hip/hip_runtime.h>
#include <hip/hip_fp16.h>
#include <math.h>

static constexpr int D = 128;
static constexpr int CAP = 64;            // bucket capacity; max degree ~45 for E/N=16 Poisson
static constexpr float EPS_BN = 1e-3f;

typedef short short8 __attribute__((ext_vector_type(8)));
typedef short short4v __attribute__((ext_vector_type(4)));
typedef float float4v __attribute__((ext_vector_type(4)));

__device__ __forceinline__ float gelu_exact(float x) {
    return 0.5f * x * (1.0f + erff(x * 0.70710678118654752f));
}

__device__ __forceinline__ void f32_to_hilo(float f, short& h, short& l) {
    unsigned u = __float_as_uint(f);
    h = (short)(u >> 16);
    float hf = __uint_as_float(u & 0xFFFF0000u);
    unsigned lu = __float_as_uint(f - hf);
    l = (short)(lu >> 16);
}

__device__ __forceinline__ short f32_to_bf16_rne(float f) {
    unsigned u = __float_as_uint(f);
    u += 0x7FFFu + ((u >> 16) & 1u);
    return (short)(u >> 16);
}

// ---------------- fold args ----------------
struct FoldArgs {
    const float* g[6]; const float* be[6]; const float* mu[6];
    const float* var[6]; const float* w[6]; const float* bi[6];
    short* wh[6]; short* wl[6]; float* bp[6]; int K[6];
};

// ---------------- BN fold: W' = diag(a) W -> bf16 hi/lo, b' = bi + (be - mu*a)W ----------------
__global__ void k_fold_all(FoldArgs fa) {
    const int f = blockIdx.y;
    const int c = blockIdx.x; // 0..127
    const int K = fa.K[f];
    const float* g = fa.g[f]; const float* be = fa.be[f];
    const float* mu = fa.mu[f]; const float* var = fa.var[f];
    const float* w = fa.w[f]; const float* bi = fa.bi[f];
    short* wh = fa.wh[f]; short* wl = fa.wl[f]; float* bp = fa.bp[f];
    float part = 0.f;
    for (int k = threadIdx.x; k < K; k += blockDim.x) {
        float a = g[k] / sqrtf(var[k] + EPS_BN);
        float wv = w[k * D + c];
        float prod = a * wv;
        short hh, ll;
        f32_to_hilo(prod, hh, ll);
        wh[c * K + k] = hh;
        wl[c * K + k] = ll;
        part += (be[k] - mu[k] * a) * wv;
    }
    for (int off = 32; off > 0; off >>= 1) part += __shfl_down(part, off, 64);
    __shared__ float sm[4];
    int lane = threadIdx.x & 63, wv_ = threadIdx.x >> 6;
    if (lane == 0) sm[wv_] = part;
    __syncthreads();
    if (threadIdx.x == 0) bp[c] = bi[c] + sm[0] + sm[1] + sm[2] + sm[3];
}

// ---------------- FFN GEMM body: out = gelu(A @ W' + b'), opts l2norm+resid / fp16-out
// W read directly from global (L2-resident broadcast) — no LDS W buffer.
// A1 (K=256 upper half) is fp16 'red', scaled by inv=1/sums[0] during staging.
template<int K, bool L2RES, bool OUT16, bool SPLIT3>
__device__ __forceinline__ void ffn_body(
    short (*__restrict__ Abuf)[128][72], float (*__restrict__ rs)[2],
    int rowBlock,
    const float* __restrict__ A0, const __half* __restrict__ A1,
    const float* __restrict__ sums,
    const short* __restrict__ Wh, const short* __restrict__ Wl,
    const float* __restrict__ bp, const float* __restrict__ resid,
    float* __restrict__ outf, __half* __restrict__ outh, int nrows)
{
    const int tid = threadIdx.x;
    const int lane = tid & 63;
    const int wv = tid >> 6;
    const int wr = wv >> 1;
    const int wc = wv & 1;
    const int m = lane & 15;
    const int quad = lane >> 4;

    float inv = 1.0f;
    if (K == 256) inv = 1.0f / sums[0];

    float4v acc[4][4];
    #pragma unroll
    for (int ti = 0; ti < 4; ti++)
        #pragma unroll
        for (int tj = 0; tj < 4; tj++)
            acc[ti][tj] = (float4v){0.f, 0.f, 0.f, 0.f};

    for (int cc = 0; cc < K / 64; cc++) {
        const int kb = (K == 256) ? ((cc & 1) * 64) : (cc * 64);
        const int kw = cc * 64;
        const bool useA1 = (K == 256 && cc >= 2);

        if (!useA1) {
            // stage 128 rows x 64 k from fp32 A0
            #pragma unroll
            for (int t = 0; t < 8; t++) {
                int i = tid + t * 256;
                int r = i >> 4, k4 = i & 15;
                int grow = rowBlock + r; if (grow >= nrows) grow = nrows - 1;
                float4 f = *((const float4*)(A0 + (size_t)grow * D + kb) + k4);
                if (SPLIT3) {
                    short h0, l0, h1, l1, h2, l2, h3, l3;
                    f32_to_hilo(f.x, h0, l0);
                    f32_to_hilo(f.y, h1, l1);
                    f32_to_hilo(f.z, h2, l2);
                    f32_to_hilo(f.w, h3, l3);
                    short4v hh = {h0, h1, h2, h3};
                    short4v ll = {l0, l1, l2, l3};
                    *(short4v*)&Abuf[0][r][k4 * 4] = hh;
                    *(short4v*)&Abuf[1][r][k4 * 4] = ll;
                } else {
                    short4v hh = {f32_to_bf16_rne(f.x), f32_to_bf16_rne(f.y),
                                  f32_to_bf16_rne(f.z), f32_to_bf16_rne(f.w)};
                    *(short4v*)&Abuf[0][r][k4 * 4] = hh;
                }
            }
        } else {
            // stage 128 rows x 64 k from fp16 A1 (red), scale by inv
            #pragma unroll
            for (int t = 0; t < 4; t++) {
                int i = tid + t * 256;
                int r = i >> 3, g8 = i & 7;
                int grow = rowBlock + r; if (grow >= nrows) grow = nrows - 1;
                float4 raw = *((const float4*)(A1 + (size_t)grow * D + kb) + g8);
                const __half2* hp = (const __half2*)&raw;
                short hs[8], ls[8];
                #pragma unroll
                for (int j = 0; j < 4; j++) {
                    float2 fv = __half22float2(hp[j]);
                    f32_to_hilo(fv.x * inv, hs[2 * j], ls[2 * j]);
                    f32_to_hilo(fv.y * inv, hs[2 * j + 1], ls[2 * j + 1]);
                }
                short8 hv = {hs[0], hs[1], hs[2], hs[3], hs[4], hs[5], hs[6], hs[7]};
                short8 lv = {ls[0], ls[1], ls[2], ls[3], ls[4], ls[5], ls[6], ls[7]};
                *(short8*)&Abuf[0][r][g8 * 8] = hv;
                *(short8*)&Abuf[1][r][g8 * 8] = lv;
            }
        }
        __syncthreads();

        #pragma unroll
        for (int ks = 0; ks < 2; ks++) {
            short8 ah[4], bh[4];
            #pragma unroll
            for (int ti = 0; ti < 4; ti++)
                ah[ti] = *(const short8*)&Abuf[0][wr * 64 + ti * 16 + m][ks * 32 + quad * 8];
            #pragma unroll
            for (int tj = 0; tj < 4; tj++)
                bh[tj] = *(const short8*)(Wh + (size_t)(wc * 64 + tj * 16 + m) * K + kw + ks * 32 + quad * 8);
            if (SPLIT3) {
                short8 al[4], bl[4];
                #pragma unroll
                for (int ti = 0; ti < 4; ti++)
                    al[ti] = *(const short8*)&Abuf[1][wr * 64 + ti * 16 + m][ks * 32 + quad * 8];
                #pragma unroll
                for (int tj = 0; tj < 4; tj++)
                    bl[tj] = *(const short8*)(Wl + (size_t)(wc * 64 + tj * 16 + m) * K + kw + ks * 32 + quad * 8);
                #pragma unroll
                for (int ti = 0; ti < 4; ti++)
                    #pragma unroll
                    for (int tj = 0; tj < 4; tj++) {
                        acc[ti][tj] = __builtin_amdgcn_mfma_f32_16x16x32_bf16(al[ti], bh[tj], acc[ti][tj], 0, 0, 0);
                        acc[ti][tj] = __builtin_amdgcn_mfma_f32_16x16x32_bf16(ah[ti], bl[tj], acc[ti][tj], 0, 0, 0);
                        acc[ti][tj] = __builtin_amdgcn_mfma_f32_16x16x32_bf16(ah[ti], bh[tj], acc[ti][tj], 0, 0, 0);
                    }
            } else {
                #pragma unroll
                for (int ti = 0; ti < 4; ti++)
                    #pragma unroll
                    for (int tj = 0; tj < 4; tj++)
                        acc[ti][tj] = __builtin_amdgcn_mfma_f32_16x16x32_bf16(ah[ti], bh[tj], acc[ti][tj], 0, 0, 0);
            }
        }
        __syncthreads();
    }

    float bvv[4];
    #pragma unroll
    for (int tj = 0; tj < 4; tj++) bvv[tj] = bp[wc * 64 + tj * 16 + m];

    float g[4][4][4];
    #pragma unroll
    for (int ti = 0; ti < 4; ti++)
        #pragma unroll
        for (int tj = 0; tj < 4; tj++)
            #pragma unroll
            for (int r4 = 0; r4 < 4; r4++)
                g[ti][tj][r4] = gelu_exact(acc[ti][tj][r4] + bvv[tj]);

    if (L2RES) {
        #pragma unroll
        for (int ti = 0; ti < 4; ti++)
            #pragma unroll
            for (int r4 = 0; r4 < 4; r4++) {
                float ss = 0.f;
                #pragma unroll
                for (int tj = 0; tj < 4; tj++) ss += g[ti][tj][r4] * g[ti][tj][r4];
                ss += __shfl_xor(ss, 1, 64);
                ss += __shfl_xor(ss, 2, 64);
                ss += __shfl_xor(ss, 4, 64);
                ss += __shfl_xor(ss, 8, 64);
                if (m == 0) rs[wr * 64 + ti * 16 + quad * 4 + r4][wc] = ss;
            }
        __syncthreads();
        #pragma unroll
        for (int ti = 0; ti < 4; ti++)
            #pragma unroll
            for (int r4 = 0; r4 < 4; r4++) {
                int rib = wr * 64 + ti * 16 + quad * 4 + r4;
                float tot = rs[rib][0] + rs[rib][1];
                float invn = 1.0f / fmaxf(sqrtf(tot), 1e-12f);
                int row = rowBlock + rib;
                if (row < nrows) {
                    #pragma unroll
                    for (int tj = 0; tj < 4; tj++) {
                        int c = wc * 64 + tj * 16 + m;
                        outf[(size_t)row * D + c] = g[ti][tj][r4] * invn + resid[(size_t)row * D + c];
                    }
                }
            }
    } else {
        #pragma unroll
        for (int ti = 0; ti < 4; ti++)
            #pragma unroll
            for (int r4 = 0; r4 < 4; r4++) {
                int row = rowBlock + wr * 64 + ti * 16 + quad * 4 + r4;
                if (row < nrows) {
                    #pragma unroll
                    for (int tj = 0; tj < 4; tj++) {
                        int c = wc * 64 + tj * 16 + m;
                        if (OUT16) outh[(size_t)row * D + c] = __float2half(g[ti][tj][r4]);
                        else       outf[(size_t)row * D + c] = g[ti][tj][r4];
                    }
                }
            }
    }
}

// ---------------- pair1 FUSED with bucket fill: blocks [0,FB) fill, rest do pre+conv1-prep
__global__ __launch_bounds__(256, 3) void k_pair1f(
    const int* __restrict__ edges, const float* __restrict__ ew,
    int* __restrict__ cnt, float* __restrict__ sums, unsigned* __restrict__ cw,
    const float* __restrict__ nf,
    const short* __restrict__ Wh0, const short* __restrict__ Wl0, const float* __restrict__ Bp0,
    float* __restrict__ xA,
    const short* __restrict__ Wh1, const float* __restrict__ Bp1,
    __half* __restrict__ yh, int E, int N, int FB)
{
    __shared__ short Abuf[2][128][72];
    __shared__ float rs[128][2];
    __shared__ float sm4[4];

    if ((int)blockIdx.x < FB) {
        // XCD-partitioned bucket fill + ew-sum (perf-only %8->XCD heuristic)
        const int tid = threadIdx.x;
        const int lane = tid & 63, wvi = tid >> 6;
        const int g = blockIdx.x & 7;
        const int bid = blockIdx.x >> 3;
        const int gstride = (FB >> 3) * 256;
        const int N8 = (N + 7) >> 3;
        const int lo = g * N8;
        const int hi = min(lo + N8, N);
        float s = 0.f;
        for (int e = bid * 256 + tid; e < E; e += gstride) {
            int dst = edges[e];
            if (dst >= lo && dst < hi) {
                int src = edges[E + e];
                float w = ew[e];
                s += w;
                unsigned short wb = __half_as_ushort(__float2half(w));
                int idx = atomicAdd(&cnt[dst], 1);
                if (idx < CAP)
                    cw[(size_t)dst * CAP + idx] = ((unsigned)src << 16) | (unsigned)wb;
            }
        }
        for (int off = 32; off > 0; off >>= 1) s += __shfl_down(s, off, 64);
        if (lane == 0) sm4[wvi] = s;
        __syncthreads();
        if (tid == 0) {
            float t = sm4[0] + sm4[1] + sm4[2] + sm4[3];
            if (t != 0.f) atomicAdd(sums, t);
        }
        return;
    }

    int rowBlock = ((int)blockIdx.x - FB) * 128;
    ffn_body<128, false, false, true>(Abuf, rs, rowBlock, nf, nullptr, nullptr, Wh0, Wl0, Bp0, nullptr, xA, nullptr, N);
    __syncthreads();
    ffn_body<128, false, true, false>(Abuf, rs, rowBlock, xA, nullptr, nullptr, Wh1, nullptr, Bp1, nullptr, nullptr, yh, N);
}

// ---------------- pair2: conv1-update (+l2norm+resid) + conv2-prepare
__global__ __launch_bounds__(256, 3) void k_pair2(
    const float* __restrict__ xA, const __half* __restrict__ red, const float* __restrict__ sums,
    const short* __restrict__ Wh2, const short* __restrict__ Wl2, const float* __restrict__ Bp2,
    float* __restrict__ y,
    const short* __restrict__ Wh3, const float* __restrict__ Bp3,
    __half* __restrict__ yh, int N)
{
    __shared__ short Abuf[2][128][72];
    __shared__ float rs[128][2];
    int rowBlock = blockIdx.x * 128;
    ffn_body<256, true, false, true>(Abuf, rs, rowBlock, xA, red, sums, Wh2, Wl2, Bp2, xA, y, nullptr, N);
    __syncthreads();
    ffn_body<128, false, true, false>(Abuf, rs, rowBlock, y, nullptr, nullptr, Wh3, nullptr, Bp3, nullptr, nullptr, yh, N);
}

// ---------------- pair3: conv2-update (+l2norm+resid) + post (fp16 logits input -> yh)
__global__ __launch_bounds__(256, 3) void k_pair3(
    const float* __restrict__ y, const __half* __restrict__ red, const float* __restrict__ sums,
    const short* __restrict__ Wh4, const short* __restrict__ Wl4, const float* __restrict__ Bp4,
    float* __restrict__ xA,
    const short* __restrict__ Wh5, const short* __restrict__ Wl5, const float* __restrict__ Bp5,
    __half* __restrict__ yh, int N)
{
    __shared__ short Abuf[2][128][72];
    __shared__ float rs[128][2];
    int rowBlock = blockIdx.x * 128;
    ffn_body<256, true, false, true>(Abuf, rs, rowBlock, y, red, sums, Wh4, Wl4, Bp4, y, xA, nullptr, N);
    __syncthreads();
    ffn_body<128, false, true, true>(Abuf, rs, rowBlock, xA, nullptr, nullptr, Wh5, Wl5, Bp5, nullptr, nullptr, yh, N);
}

// ---------------- bucket gather-reduce: red[n] = sum_e ew[e]*y[col[e]]  (UNSCALED, fp16 out)
__global__ void k_reduce(const int* __restrict__ cnt, const unsigned* __restrict__ cw,
                         const __half* __restrict__ y, __half* __restrict__ red, int N) {
    int n = blockIdx.x * (blockDim.x >> 6) + (threadIdx.x >> 6);
    if (n >= N) return;
    int lane = threadIdx.x & 63;
    int sub = lane >> 4;      // edge slot 0..3
    int q = lane & 15;        // 8-half chunk
    int count = min(cnt[n], CAP);
    int start = n * CAP;
    int end = start + count;
    float acc[8] = {0.f, 0.f, 0.f, 0.f, 0.f, 0.f, 0.f, 0.f};
    int i = start + sub;
    if (i < end) {
        unsigned c = cw[i];
        for (;;) {
            int ni = i + 4;
            unsigned nc = 0;
            if (ni < end) nc = cw[ni];
            int src = (int)(c >> 16);
            float w = __half2float(__ushort_as_half((unsigned short)(c & 0xFFFFu)));
            float4 raw = *((const float4*)(y + (size_t)src * D) + q);  // 8 halves, 16B
            const __half2* hp = (const __half2*)&raw;
            #pragma unroll
            for (int t = 0; t < 4; t++) {
                float2 f = __half22float2(hp[t]);
                acc[t * 2]     += w * f.x;
                acc[t * 2 + 1] += w * f.y;
            }
            if (ni >= end) break;
            i = ni; c = nc;
        }
    }
    #pragma unroll
    for (int t = 0; t < 8; t++) {
        acc[t] += __shfl_xor(acc[t], 16, 64);
        acc[t] += __shfl_xor(acc[t], 32, 64);
    }
    if (sub == 0) {
        float4 ov;
        __half2* op = (__half2*)&ov;
        #pragma unroll
        for (int t = 0; t < 4; t++)
            op[t] = __floats2half2_rn(acc[t * 2], acc[t * 2 + 1]);
        *((float4*)(red + (size_t)n * D + q * 8)) = ov;
    }
}

// ---------------- gather + logits (fp16 x) ----------------
__global__ void k_logits(const __half* __restrict__ x, const int* __restrict__ idx,
                         const float* __restrict__ LW, const float* __restrict__ lb,
                         float* __restrict__ out, int B) {
    int wid = blockIdx.x * 4 + (threadIdx.x >> 6);
    int lane = threadIdx.x & 63;
    if (wid >= B) return;
    int row = __builtin_amdgcn_readfirstlane(idx[wid]);
    if (lane >= 40) return;
    float acc = lb[lane];
    const float4* xr = (const float4*)(x + (size_t)row * D);
    #pragma unroll 4
    for (int k8 = 0; k8 < 16; k8++) {
        float4 raw = xr[k8];
        const __half2* hp = (const __half2*)&raw;
        #pragma unroll
        for (int j = 0; j < 4; j++) {
            float2 f = __half22float2(hp[j]);
            acc += f.x * LW[(k8 * 8 + 2 * j) * 40 + lane];
            acc += f.y * LW[(k8 * 8 + 2 * j + 1) * 40 + lane];
        }
    }
    out[(size_t)wid * 40 + lane] = acc;
}

extern "C" void kernel_launch(void* const* d_in, const int* in_sizes, int n_in,
                              void* d_out, int out_size, void* d_ws, size_t ws_size,
                              hipStream_t stream) {
    const float* node_features = (const float*)d_in[0];
    const int*   edges         = (const int*)d_in[1];
    const float* edge_w        = (const float*)d_in[2];
    const int*   input_idx     = (const int*)d_in[3];
    const int N = in_sizes[0] / D;
    const int E = in_sizes[2];
    const int B = in_sizes[3];

    const float* P[6][6];
    for (int f = 0; f < 6; f++)
        for (int q = 0; q < 6; q++)
            P[f][q] = (const float*)d_in[4 + f * 6 + q];
    const float* logits_w = (const float*)d_in[40];
    const float* logits_b = (const float*)d_in[41];

    float* ws = (float*)d_ws;
    size_t nd = (size_t)N * D;
    float* xA  = ws;
    float* y   = ws + nd;
    float* p   = ws + 2 * nd;
    __half* redh = (__half*)p; p += nd / 2;     // fp16 unscaled reduce output
    __half* yh   = (__half*)p; p += nd / 2;     // fp16 messages / logits input
    const int Ks[6] = {128, 128, 256, 128, 256, 128};
    short* Wh[6]; short* Wl[6]; float* Bp[6];
    {
        short* sp = (short*)p;
        for (int f = 0; f < 6; f++) {
            Wh[f] = sp; sp += (size_t)Ks[f] * D;
            Wl[f] = sp; sp += (size_t)Ks[f] * D;
        }
        p = (float*)sp;
    }
    for (int f = 0; f < 6; f++) { Bp[f] = p; p += D; }
    int* cnt    = (int*)p; p += N;
    float* sums = p; p += 2;                        // adjacent to cnt: single memset
    unsigned* cw = (unsigned*)p; p += (size_t)N * CAP;  // packed buckets (src<<16 | fp16 w)

    FoldArgs fa;
    for (int f = 0; f < 6; f++) {
        fa.g[f] = P[f][0]; fa.be[f] = P[f][1]; fa.mu[f] = P[f][2];
        fa.var[f] = P[f][3]; fa.w[f] = P[f][4]; fa.bi[f] = P[f][5];
        fa.wh[f] = Wh[f]; fa.wl[f] = Wl[f]; fa.bp[f] = Bp[f]; fa.K[f] = Ks[f];
    }

    const int gb = (N + 127) / 128;
    const int rb = (N + 3) / 4;
    const int FB = 1024;  // fill blocks: 128 x 8 XCD groups

    hipMemsetAsync(cnt, 0, ((size_t)N + 2) * sizeof(int), stream);
    k_fold_all<<<dim3(D, 6), 256, 0, stream>>>(fa);
    // pre + conv1-prepare, with bucket fill fused as extra blocks (hidden under BW-bound FFN)
    k_pair1f<<<FB + gb, 256, 0, stream>>>(edges, edge_w, cnt, sums, cw,
                                          node_features, Wh[0], Wl[0], Bp[0], xA,
                                          Wh[1], Bp[1], yh, E, N, FB);
    k_reduce<<<rb, 256, 0, stream>>>(cnt, cw, yh, redh, N);
    k_pair2<<<gb, 256, 0, stream>>>(xA, redh, sums, Wh[2], Wl[2], Bp[2], y, Wh[3], Bp[3], yh, N);
    k_reduce<<<rb, 256, 0, stream>>>(cnt, cw, yh, redh, N);
    k_pair3<<<gb, 256, 0, stream>>>(y, redh, sums, Wh[4], Wl[4], Bp[4], xA, Wh[5], Wl[5], Bp[5], yh, N);
    k_logits<<<(B + 3) / 4, 256, 0, stream>>>(yh, input_idx, logits_w, logits_b, (float*)d_out, B);
}

// Round 11
// 476.930 us; speedup vs baseline: 1.0921x; 1.0921x over previous
//
#include <hip/hip_runtime.h>
#include <hip/hip_fp16.h>
#include <math.h>

static constexpr int D = 128;
static constexpr int CAP = 64;            // bucket capacity; max degree ~45 for E/N=16 Poisson
static constexpr int ST = 40;             // LDS row stride (shorts): 16B-aligned, 2-way-free banks
static constexpr float EPS_BN = 1e-3f;

typedef short short8 __attribute__((ext_vector_type(8)));
typedef short short4v __attribute__((ext_vector_type(4)));
typedef float float4v __attribute__((ext_vector_type(4)));

__device__ __forceinline__ float gelu_exact(float x) {
    return 0.5f * x * (1.0f + erff(x * 0.70710678118654752f));
}

__device__ __forceinline__ void f32_to_hilo(float f, short& h, short& l) {
    unsigned u = __float_as_uint(f);
    h = (short)(u >> 16);
    float hf = __uint_as_float(u & 0xFFFF0000u);
    unsigned lu = __float_as_uint(f - hf);
    l = (short)(lu >> 16);
}

__device__ __forceinline__ short f32_to_bf16_rne(float f) {
    unsigned u = __float_as_uint(f);
    u += 0x7FFFu + ((u >> 16) & 1u);
    return (short)(u >> 16);
}

// ---------------- fold args ----------------
struct FoldArgs {
    const float* g[6]; const float* be[6]; const float* mu[6];
    const float* var[6]; const float* w[6]; const float* bi[6];
    short* wh[6]; short* wl[6]; float* bp[6]; int K[6];
};

// ---------------- fused build: XCD-partitioned bucket fill + ew-sum + BN fold ----------------
__global__ void k_build(const int* __restrict__ edges, const float* __restrict__ ew,
                        int* __restrict__ cnt, float* __restrict__ sums,
                        unsigned* __restrict__ cw, FoldArgs fa, int E, int N, int fillBlocks) {
    __shared__ float sm[4];
    const int tid = threadIdx.x;
    const int lane = tid & 63, wvi = tid >> 6;

    if ((int)blockIdx.x < fillBlocks) {
        const int g = blockIdx.x & 7;
        const int bid = blockIdx.x >> 3;
        const int gstride = (fillBlocks >> 3) * 256;
        const int N8 = (N + 7) >> 3;
        const int lo = g * N8;
        const int hi = min(lo + N8, N);
        float s = 0.f;
        for (int e = bid * 256 + tid; e < E; e += gstride) {
            int dst = edges[e];
            if (dst >= lo && dst < hi) {
                int src = edges[E + e];
                float w = ew[e];
                s += w;
                unsigned short wb = __half_as_ushort(__float2half(w));
                int idx = atomicAdd(&cnt[dst], 1);
                if (idx < CAP)
                    cw[(size_t)dst * CAP + idx] = ((unsigned)src << 16) | (unsigned)wb;
            }
        }
        for (int off = 32; off > 0; off >>= 1) s += __shfl_down(s, off, 64);
        if (lane == 0) sm[wvi] = s;
        __syncthreads();
        if (tid == 0) {
            float t = sm[0] + sm[1] + sm[2] + sm[3];
            if (t != 0.f) atomicAdd(sums, t);
        }
    } else {
        const int idx = blockIdx.x - fillBlocks;
        const int f = idx >> 7;      // 0..5
        const int c = idx & 127;     // 0..127
        const int K = fa.K[f];
        const float* g = fa.g[f]; const float* be = fa.be[f];
        const float* mu = fa.mu[f]; const float* var = fa.var[f];
        const float* w = fa.w[f]; const float* bi = fa.bi[f];
        short* wh = fa.wh[f]; short* wl = fa.wl[f]; float* bp = fa.bp[f];
        float part = 0.f;
        for (int k = tid; k < K; k += blockDim.x) {
            float a = g[k] / sqrtf(var[k] + EPS_BN);
            float wv = w[k * D + c];
            float prod = a * wv;
            short hh, ll;
            f32_to_hilo(prod, hh, ll);
            wh[c * K + k] = hh;
            wl[c * K + k] = ll;
            part += (be[k] - mu[k] * a) * wv;
        }
        for (int off = 32; off > 0; off >>= 1) part += __shfl_down(part, off, 64);
        if (lane == 0) sm[wvi] = part;
        __syncthreads();
        if (tid == 0) bp[c] = bi[c] + sm[0] + sm[1] + sm[2] + sm[3];
    }
}

// ---------------- bucket gather-reduce: red[n] = sum_e ew[e]*y[col[e]]  (UNSCALED, fp16 out)
__global__ void k_reduce(const int* __restrict__ cnt, const unsigned* __restrict__ cw,
                         const __half* __restrict__ y, __half* __restrict__ red, int N) {
    int n = blockIdx.x * (blockDim.x >> 6) + (threadIdx.x >> 6);
    if (n >= N) return;
    int lane = threadIdx.x & 63;
    int sub = lane >> 4;      // edge slot 0..3
    int q = lane & 15;        // 8-half chunk
    int count = min(cnt[n], CAP);
    int start = n * CAP;
    int end = start + count;
    float acc[8] = {0.f, 0.f, 0.f, 0.f, 0.f, 0.f, 0.f, 0.f};
    int i = start + sub;
    if (i < end) {
        unsigned c = cw[i];
        for (;;) {
            int ni = i + 4;
            unsigned nc = 0;
            if (ni < end) nc = cw[ni];
            int src = (int)(c >> 16);
            float w = __half2float(__ushort_as_half((unsigned short)(c & 0xFFFFu)));
            float4 raw = *((const float4*)(y + (size_t)src * D) + q);  // 8 halves, 16B
            const __half2* hp = (const __half2*)&raw;
            #pragma unroll
            for (int t = 0; t < 4; t++) {
                float2 f = __half22float2(hp[t]);
                acc[t * 2]     += w * f.x;
                acc[t * 2 + 1] += w * f.y;
            }
            if (ni >= end) break;
            i = ni; c = nc;
        }
    }
    #pragma unroll
    for (int t = 0; t < 8; t++) {
        acc[t] += __shfl_xor(acc[t], 16, 64);
        acc[t] += __shfl_xor(acc[t], 32, 64);
    }
    if (sub == 0) {
        float4 ov;
        __half2* op = (__half2*)&ov;
        #pragma unroll
        for (int t = 0; t < 4; t++)
            op[t] = __floats2half2_rn(acc[t * 2], acc[t * 2 + 1]);
        *((float4*)(red + (size_t)n * D + q * 8)) = ov;
    }
}

// ---------------- FFN GEMM body: out = gelu(A @ W' + b'), opts l2norm+resid / fp16-out
// KC=32 K-chunks: LDS 42 KB/block -> 3 blocks/CU. A and W both staged in LDS (coalesced).
// A1 (K=256 upper half) is fp16 unscaled 'red'; scaled by 1/sums[0] during staging.
template<int K, bool L2RES, bool OUT16, bool SPLIT3>
__device__ __forceinline__ void ffn_body(
    short (*__restrict__ Abuf)[128][ST], short (*__restrict__ Wbuf)[128][ST],
    float (*__restrict__ rs)[2], int rowBlock,
    const float* __restrict__ A0, const __half* __restrict__ A1,
    const float* __restrict__ sums,
    const short* __restrict__ Wh, const short* __restrict__ Wl,
    const float* __restrict__ bp, const float* __restrict__ resid,
    float* __restrict__ outf, __half* __restrict__ outh, int nrows)
{
    const int tid = threadIdx.x;
    const int lane = tid & 63;
    const int wv = tid >> 6;
    const int wr = wv >> 1;
    const int wc = wv & 1;
    const int m = lane & 15;
    const int quad = lane >> 4;

    float inv = 1.0f;
    if (K == 256) inv = 1.0f / sums[0];

    float4v acc[4][4];
    #pragma unroll
    for (int ti = 0; ti < 4; ti++)
        #pragma unroll
        for (int tj = 0; tj < 4; tj++)
            acc[ti][tj] = (float4v){0.f, 0.f, 0.f, 0.f};

    for (int cc = 0; cc < K / 32; cc++) {
        const int kw = cc * 32;
        const bool useA1 = (K == 256 && cc >= 4);
        const int kb = (K == 256) ? ((cc & 3) * 32) : kw;

        if (!useA1) {
            // stage 128 rows x 32 k from fp32 A0 (8 float4 per row)
            #pragma unroll
            for (int t = 0; t < 4; t++) {
                int i = tid + t * 256;
                int r = i >> 3, k4 = i & 7;
                int grow = rowBlock + r; if (grow >= nrows) grow = nrows - 1;
                float4 f = *((const float4*)(A0 + (size_t)grow * D + kb) + k4);
                if (SPLIT3) {
                    short h0, l0, h1, l1, h2, l2, h3, l3;
                    f32_to_hilo(f.x, h0, l0);
                    f32_to_hilo(f.y, h1, l1);
                    f32_to_hilo(f.z, h2, l2);
                    f32_to_hilo(f.w, h3, l3);
                    short4v hh = {h0, h1, h2, h3};
                    short4v ll = {l0, l1, l2, l3};
                    *(short4v*)&Abuf[0][r][k4 * 4] = hh;
                    *(short4v*)&Abuf[1][r][k4 * 4] = ll;
                } else {
                    short4v hh = {f32_to_bf16_rne(f.x), f32_to_bf16_rne(f.y),
                                  f32_to_bf16_rne(f.z), f32_to_bf16_rne(f.w)};
                    *(short4v*)&Abuf[0][r][k4 * 4] = hh;
                }
            }
        } else {
            // stage 128 rows x 32 k from fp16 A1 (red), scale by inv (4 x 16B chunks per row)
            #pragma unroll
            for (int t = 0; t < 2; t++) {
                int i = tid + t * 256;
                int r = i >> 2, g8 = i & 3;
                int grow = rowBlock + r; if (grow >= nrows) grow = nrows - 1;
                float4 raw = *((const float4*)(A1 + (size_t)grow * D + kb) + g8);
                const __half2* hp = (const __half2*)&raw;
                short hs[8], ls[8];
                #pragma unroll
                for (int j = 0; j < 4; j++) {
                    float2 fv = __half22float2(hp[j]);
                    f32_to_hilo(fv.x * inv, hs[2 * j], ls[2 * j]);
                    f32_to_hilo(fv.y * inv, hs[2 * j + 1], ls[2 * j + 1]);
                }
                short8 hv = {hs[0], hs[1], hs[2], hs[3], hs[4], hs[5], hs[6], hs[7]};
                short8 lv = {ls[0], ls[1], ls[2], ls[3], ls[4], ls[5], ls[6], ls[7]};
                *(short8*)&Abuf[0][r][g8 * 8] = hv;
                *(short8*)&Abuf[1][r][g8 * 8] = lv;
            }
        }
        // stage W: 128 cols x 32 k bf16 (4 x 16B chunks per col), coalesced
        #pragma unroll
        for (int t = 0; t < 2; t++) {
            int i = tid + t * 256;
            int c = i >> 2, g = i & 3;
            *(short8*)&Wbuf[0][c][g * 8] = *(const short8*)(Wh + (size_t)c * K + kw + g * 8);
            if (SPLIT3)
                *(short8*)&Wbuf[1][c][g * 8] = *(const short8*)(Wl + (size_t)c * K + kw + g * 8);
        }
        __syncthreads();

        short8 ah[4], bh[4];
        #pragma unroll
        for (int ti = 0; ti < 4; ti++)
            ah[ti] = *(const short8*)&Abuf[0][wr * 64 + ti * 16 + m][quad * 8];
        #pragma unroll
        for (int tj = 0; tj < 4; tj++)
            bh[tj] = *(const short8*)&Wbuf[0][wc * 64 + tj * 16 + m][quad * 8];
        if (SPLIT3) {
            short8 al[4], bl[4];
            #pragma unroll
            for (int ti = 0; ti < 4; ti++)
                al[ti] = *(const short8*)&Abuf[1][wr * 64 + ti * 16 + m][quad * 8];
            #pragma unroll
            for (int tj = 0; tj < 4; tj++)
                bl[tj] = *(const short8*)&Wbuf[1][wc * 64 + tj * 16 + m][quad * 8];
            #pragma unroll
            for (int ti = 0; ti < 4; ti++)
                #pragma unroll
                for (int tj = 0; tj < 4; tj++) {
                    acc[ti][tj] = __builtin_amdgcn_mfma_f32_16x16x32_bf16(al[ti], bh[tj], acc[ti][tj], 0, 0, 0);
                    acc[ti][tj] = __builtin_amdgcn_mfma_f32_16x16x32_bf16(ah[ti], bl[tj], acc[ti][tj], 0, 0, 0);
                    acc[ti][tj] = __builtin_amdgcn_mfma_f32_16x16x32_bf16(ah[ti], bh[tj], acc[ti][tj], 0, 0, 0);
                }
        } else {
            #pragma unroll
            for (int ti = 0; ti < 4; ti++)
                #pragma unroll
                for (int tj = 0; tj < 4; tj++)
                    acc[ti][tj] = __builtin_amdgcn_mfma_f32_16x16x32_bf16(ah[ti], bh[tj], acc[ti][tj], 0, 0, 0);
        }
        __syncthreads();
    }

    float bvv[4];
    #pragma unroll
    for (int tj = 0; tj < 4; tj++) bvv[tj] = bp[wc * 64 + tj * 16 + m];

    float g[4][4][4];
    #pragma unroll
    for (int ti = 0; ti < 4; ti++)
        #pragma unroll
        for (int tj = 0; tj < 4; tj++)
            #pragma unroll
            for (int r4 = 0; r4 < 4; r4++)
                g[ti][tj][r4] = gelu_exact(acc[ti][tj][r4] + bvv[tj]);

    if (L2RES) {
        #pragma unroll
        for (int ti = 0; ti < 4; ti++)
            #pragma unroll
            for (int r4 = 0; r4 < 4; r4++) {
                float ss = 0.f;
                #pragma unroll
                for (int tj = 0; tj < 4; tj++) ss += g[ti][tj][r4] * g[ti][tj][r4];
                ss += __shfl_xor(ss, 1, 64);
                ss += __shfl_xor(ss, 2, 64);
                ss += __shfl_xor(ss, 4, 64);
                ss += __shfl_xor(ss, 8, 64);
                if (m == 0) rs[wr * 64 + ti * 16 + quad * 4 + r4][wc] = ss;
            }
        __syncthreads();
        #pragma unroll
        for (int ti = 0; ti < 4; ti++)
            #pragma unroll
            for (int r4 = 0; r4 < 4; r4++) {
                int rib = wr * 64 + ti * 16 + quad * 4 + r4;
                float tot = rs[rib][0] + rs[rib][1];
                float invn = 1.0f / fmaxf(sqrtf(tot), 1e-12f);
                int row = rowBlock + rib;
                if (row < nrows) {
                    #pragma unroll
                    for (int tj = 0; tj < 4; tj++) {
                        int c = wc * 64 + tj * 16 + m;
                        outf[(size_t)row * D + c] = g[ti][tj][r4] * invn + resid[(size_t)row * D + c];
                    }
                }
            }
    } else {
        #pragma unroll
        for (int ti = 0; ti < 4; ti++)
            #pragma unroll
            for (int r4 = 0; r4 < 4; r4++) {
                int row = rowBlock + wr * 64 + ti * 16 + quad * 4 + r4;
                if (row < nrows) {
                    #pragma unroll
                    for (int tj = 0; tj < 4; tj++) {
                        int c = wc * 64 + tj * 16 + m;
                        if (OUT16) outh[(size_t)row * D + c] = __float2half(g[ti][tj][r4]);
                        else       outf[(size_t)row * D + c] = g[ti][tj][r4];
                    }
                }
            }
    }
}

// ---------------- fused FFN pairs ----------------
__global__ __launch_bounds__(256, 3) void k_pair1(
    const float* __restrict__ nf,
    const short* __restrict__ Wh0, const short* __restrict__ Wl0, const float* __restrict__ Bp0,
    float* __restrict__ xA,
    const short* __restrict__ Wh1, const float* __restrict__ Bp1,
    __half* __restrict__ yh, int N)
{
    __shared__ short Abuf[2][128][ST];
    __shared__ short Wbuf[2][128][ST];
    __shared__ float rs[128][2];
    int rowBlock = blockIdx.x * 128;
    ffn_body<128, false, false, true>(Abuf, Wbuf, rs, rowBlock, nf, nullptr, nullptr, Wh0, Wl0, Bp0, nullptr, xA, nullptr, N);
    __syncthreads();
    ffn_body<128, false, true, false>(Abuf, Wbuf, rs, rowBlock, xA, nullptr, nullptr, Wh1, nullptr, Bp1, nullptr, nullptr, yh, N);
}

__global__ __launch_bounds__(256, 3) void k_pair2(
    const float* __restrict__ xA, const __half* __restrict__ red, const float* __restrict__ sums,
    const short* __restrict__ Wh2, const short* __restrict__ Wl2, const float* __restrict__ Bp2,
    float* __restrict__ y,
    const short* __restrict__ Wh3, const float* __restrict__ Bp3,
    __half* __restrict__ yh, int N)
{
    __shared__ short Abuf[2][128][ST];
    __shared__ short Wbuf[2][128][ST];
    __shared__ float rs[128][2];
    int rowBlock = blockIdx.x * 128;
    ffn_body<256, true, false, true>(Abuf, Wbuf, rs, rowBlock, xA, red, sums, Wh2, Wl2, Bp2, xA, y, nullptr, N);
    __syncthreads();
    ffn_body<128, false, true, false>(Abuf, Wbuf, rs, rowBlock, y, nullptr, nullptr, Wh3, nullptr, Bp3, nullptr, nullptr, yh, N);
}

__global__ __launch_bounds__(256, 3) void k_pair3(
    const float* __restrict__ y, const __half* __restrict__ red, const float* __restrict__ sums,
    const short* __restrict__ Wh4, const short* __restrict__ Wl4, const float* __restrict__ Bp4,
    float* __restrict__ xA,
    const short* __restrict__ Wh5, const short* __restrict__ Wl5, const float* __restrict__ Bp5,
    __half* __restrict__ yh, int N)
{
    __shared__ short Abuf[2][128][ST];
    __shared__ short Wbuf[2][128][ST];
    __shared__ float rs[128][2];
    int rowBlock = blockIdx.x * 128;
    ffn_body<256, true, false, true>(Abuf, Wbuf, rs, rowBlock, y, red, sums, Wh4, Wl4, Bp4, y, xA, nullptr, N);
    __syncthreads();
    ffn_body<128, false, true, true>(Abuf, Wbuf, rs, rowBlock, xA, nullptr, nullptr, Wh5, Wl5, Bp5, nullptr, nullptr, yh, N);
}

// ---------------- gather + logits (fp16 x) ----------------
__global__ void k_logits(const __half* __restrict__ x, const int* __restrict__ idx,
                         const float* __restrict__ LW, const float* __restrict__ lb,
                         float* __restrict__ out, int B) {
    int wid = blockIdx.x * 4 + (threadIdx.x >> 6);
    int lane = threadIdx.x & 63;
    if (wid >= B) return;
    int row = __builtin_amdgcn_readfirstlane(idx[wid]);
    if (lane >= 40) return;
    float acc = lb[lane];
    const float4* xr = (const float4*)(x + (size_t)row * D);
    #pragma unroll 4
    for (int k8 = 0; k8 < 16; k8++) {
        float4 raw = xr[k8];
        const __half2* hp = (const __half2*)&raw;
        #pragma unroll
        for (int j = 0; j < 4; j++) {
            float2 f = __half22float2(hp[j]);
            acc += f.x * LW[(k8 * 8 + 2 * j) * 40 + lane];
            acc += f.y * LW[(k8 * 8 + 2 * j + 1) * 40 + lane];
        }
    }
    out[(size_t)wid * 40 + lane] = acc;
}

extern "C" void kernel_launch(void* const* d_in, const int* in_sizes, int n_in,
                              void* d_out, int out_size, void* d_ws, size_t ws_size,
                              hipStream_t stream) {
    const float* node_features = (const float*)d_in[0];
    const int*   edges         = (const int*)d_in[1];
    const float* edge_w        = (const float*)d_in[2];
    const int*   input_idx     = (const int*)d_in[3];
    const int N = in_sizes[0] / D;
    const int E = in_sizes[2];
    const int B = in_sizes[3];

    const float* P[6][6];
    for (int f = 0; f < 6; f++)
        for (int q = 0; q < 6; q++)
            P[f][q] = (const float*)d_in[4 + f * 6 + q];
    const float* logits_w = (const float*)d_in[40];
    const float* logits_b = (const float*)d_in[41];

    float* ws = (float*)d_ws;
    size_t nd = (size_t)N * D;
    float* xA  = ws;
    float* y   = ws + nd;
    float* p   = ws + 2 * nd;
    __half* redh = (__half*)p; p += nd / 2;     // fp16 unscaled reduce output
    __half* yh   = (__half*)p; p += nd / 2;     // fp16 messages / logits input
    const int Ks[6] = {128, 128, 256, 128, 256, 128};
    short* Wh[6]; short* Wl[6]; float* Bp[6];
    {
        short* sp = (short*)p;
        for (int f = 0; f < 6; f++) {
            Wh[f] = sp; sp += (size_t)Ks[f] * D;
            Wl[f] = sp; sp += (size_t)Ks[f] * D;
        }
        p = (float*)sp;
    }
    for (int f = 0; f < 6; f++) { Bp[f] = p; p += D; }
    int* cnt    = (int*)p; p += N;
    float* sums = p; p += 2;                        // adjacent to cnt: single memset
    unsigned* cw = (unsigned*)p; p += (size_t)N * CAP;  // packed buckets (src<<16 | fp16 w)

    FoldArgs fa;
    for (int f = 0; f < 6; f++) {
        fa.g[f] = P[f][0]; fa.be[f] = P[f][1]; fa.mu[f] = P[f][2];
        fa.var[f] = P[f][3]; fa.w[f] = P[f][4]; fa.bi[f] = P[f][5];
        fa.wh[f] = Wh[f]; fa.wl[f] = Wl[f]; fa.bp[f] = Bp[f]; fa.K[f] = Ks[f];
    }

    const int gb = (N + 127) / 128;
    const int rb = (N + 3) / 4;
    const int FB = 1024;  // fill blocks: 128 x 8 XCD groups

    hipMemsetAsync(cnt, 0, ((size_t)N + 2) * sizeof(int), stream);
    k_build<<<FB + 768, 256, 0, stream>>>(edges, edge_w, cnt, sums, cw, fa, E, N, FB);

    // pre + conv1-prepare
    k_pair1<<<gb, 256, 0, stream>>>(node_features, Wh[0], Wl[0], Bp[0], xA, Wh[1], Bp[1], yh, N);
    k_reduce<<<rb, 256, 0, stream>>>(cnt, cw, yh, redh, N);
    // conv1-update (+l2norm+resid) + conv2-prepare
    k_pair2<<<gb, 256, 0, stream>>>(xA, redh, sums, Wh[2], Wl[2], Bp[2], y, Wh[3], Bp[3], yh, N);
    k_reduce<<<rb, 256, 0, stream>>>(cnt, cw, yh, redh, N);
    // conv2-update (+l2norm+resid) + post (fp16 logits input)
    k_pair3<<<gb, 256, 0, stream>>>(y, redh, sums, Wh[4], Wl[4], Bp[4], xA, Wh[5], Wl[5], Bp[5], yh, N);
    k_logits<<<(B + 3) / 4, 256, 0, stream>>>(yh, input_idx, logits_w, logits_b, (float*)d_out, B);
}